// Round 23
// baseline (298.553 us; speedup 1.0000x reference)
//
#include <hip/hip_runtime.h>
#include <hip/hip_fp8.h>

#define DD 128
#define CC 64
#define BKW 512            // nodes per bucket
#define NPB 4096           // edges per phase-B block
#define CAP 10240          // per-bucket edge capacity (mean 8192, +22 sigma)

typedef __attribute__((ext_vector_type(8))) short short8v;
typedef __attribute__((ext_vector_type(4))) float f32x4;
typedef __attribute__((ext_vector_type(2))) float f32x2;

static __device__ inline ushort f2bf_rne(float f) {
    unsigned u = __float_as_uint(f);
    unsigned r = (u + 0x7FFFu + ((u >> 16) & 1u)) >> 16;
    return (ushort)r;
}
static __device__ inline float bf2f(ushort h) {
    return __uint_as_float(((unsigned)h) << 16);
}

// ============ bcur init: bucket b appends at b*CAP ============
__global__ void binit_kernel(int* __restrict__ bcur, int nbuck) {
    int b = blockIdx.x * 256 + threadIdx.x;
    if (b < nbuck) bcur[b] = b * CAP;
}

// ===== phase B: bin edges by bucket; packed word = src | (dst&511)<<17 ======
__global__ __launch_bounds__(256) void binA_kernel(const int* __restrict__ ei,
                                                   int* __restrict__ bcur,
                                                   uint* __restrict__ ebuf, int E) {
    __shared__ int sRun[256];
    __shared__ int sRel[256];
    __shared__ int sBase[256];
    __shared__ uint sPair[NPB];
    __shared__ unsigned char sBkt[NPB];
    __shared__ int sHist[256];
    const int t = threadIdx.x;
    const int e0 = blockIdx.x * NPB;
    const int cntE = min(NPB, E - e0);

    sHist[t] = 0;
    __syncthreads();
    for (int j = t; j < cntE; j += 256) {
        int dst = ei[E + e0 + j];
        atomicAdd(&sHist[dst >> 9], 1);
    }
    __syncthreads();
    int h = sHist[t];
    sRun[t] = h;
    __syncthreads();
    for (int off = 1; off < 256; off <<= 1) {
        int v = 0;
        if (t >= off) v = sRun[t - off];
        __syncthreads();
        if (t >= off) sRun[t] += v;
        __syncthreads();
    }
    int runstart = sRun[t] - h;
    int base = 0;
    if (h > 0) base = atomicAdd(&bcur[t], h);
    sRun[t] = runstart;
    sRel[t] = runstart;
    sBase[t] = base;
    __syncthreads();
    for (int j = t; j < cntE; j += 256) {
        int src = ei[e0 + j];
        int dst = ei[E + e0 + j];
        int b = dst >> 9;
        int slot = atomicAdd(&sRel[b], 1);
        sPair[slot] = (uint)src | ((uint)(dst & 511) << 17);
        sBkt[slot] = (unsigned char)b;
    }
    __syncthreads();
    for (int s = t; s < cntE; s += 256) {
        uint p = sPair[s];
        int b = (int)sBkt[s];
        int gpos = sBase[b] + (s - sRun[b]);
        ebuf[gpos] = p;
    }
}

// == phase C: per-bucket (region [b*CAP, bcur[b])): per-node offs/cnt + scatter ==
__global__ __launch_bounds__(256) void binB2_kernel(const uint* __restrict__ ebuf,
                                                    const int* __restrict__ bcur,
                                                    int* __restrict__ offs,
                                                    int* __restrict__ cnt,
                                                    int* __restrict__ csr, int n) {
    __shared__ int sCnt[BKW];
    __shared__ int sOffs[BKW];
    __shared__ int sScan[256];
    const int t = threadIdx.x;
    const int node0 = blockIdx.x * BKW;
    const int start = blockIdx.x * CAP;
    const int end = bcur[blockIdx.x];

    sCnt[t] = 0; sCnt[t + 256] = 0;
    __syncthreads();
    for (int j = start + t; j < end; j += 256) {
        int d = (int)(ebuf[j] >> 17);
        atomicAdd(&sCnt[d], 1);
    }
    __syncthreads();
    int v0 = sCnt[2 * t], v1 = sCnt[2 * t + 1];
    int sum = v0 + v1;
    sScan[t] = sum;
    __syncthreads();
    for (int off = 1; off < 256; off <<= 1) {
        int xv = 0;
        if (t >= off) xv = sScan[t - off];
        __syncthreads();
        if (t >= off) sScan[t] += xv;
        __syncthreads();
    }
    int excl = sScan[t] - sum;
    sOffs[2 * t] = start + excl;
    sOffs[2 * t + 1] = start + excl + v0;
    __syncthreads();
    for (int i = t; i < BKW; i += 256) {
        int node = node0 + i;
        if (node < n) { offs[node] = sOffs[i]; cnt[node] = sCnt[i]; }
    }
    __syncthreads();
    sCnt[t] = 0; sCnt[t + 256] = 0;
    __syncthreads();
    for (int j = start + t; j < end; j += 256) {
        uint p = ebuf[j];
        int d = (int)(p >> 17);
        int r = atomicAdd(&sCnt[d], 1);
        csr[sOffs[d] + r] = (int)(p & 0x1FFFFu);
    }
}

// ===== merged prep: x -> (xh bf16, xq e4m3) + wfrag + wofrag ===============
__global__ __launch_bounds__(256) void prep_kernel(
    const float* __restrict__ x, ushort* __restrict__ xh, uint* __restrict__ xq,
    const float* __restrict__ Wl1, const float* __restrict__ Wr1,
    const float* __restrict__ Wl2, const float* __restrict__ Wr2,
    const float* __restrict__ Wout,
    ushort* __restrict__ WTfrag1, ushort* __restrict__ WTfrag2,
    ushort* __restrict__ WoFrag, int nxblk) {
    const int t = threadIdx.x;
    const int bx = blockIdx.x;
    if (bx < nxblk) {
        int i = bx * 256 + t;                    // 8 elems per thread
        float4 a = ((const float4*)x)[2 * i];
        float4 b = ((const float4*)x)[2 * i + 1];
        float vv[8] = {a.x, a.y, a.z, a.w, b.x, b.y, b.z, b.w};
        ushort r[8];
        uint q[8];
        #pragma unroll
        for (int j = 0; j < 8; ++j) {
            r[j] = f2bf_rne(vv[j]);
            q[j] = (uint)__hip_fp8_e4m3(vv[j]).__x;
        }
        uint4 o;
        o.x = (uint)r[0] | ((uint)r[1] << 16);
        o.y = (uint)r[2] | ((uint)r[3] << 16);
        o.z = (uint)r[4] | ((uint)r[5] << 16);
        o.w = (uint)r[6] | ((uint)r[7] << 16);
        ((uint4*)xh)[i] = o;
        uint2 oq;
        oq.x = q[0] | (q[1] << 8) | (q[2] << 16) | (q[3] << 24);
        oq.y = q[4] | (q[5] << 8) | (q[6] << 16) | (q[7] << 24);
        ((uint2*)xq)[i] = oq;
    } else if (bx < nxblk + 32) {
        int li = bx - nxblk;
        int layer = li >> 4;
        int idx = (li & 15) * 256 + t;           // [0, 4096)
        const float* Wl = layer ? Wl2 : Wl1;
        const float* Wr = layer ? Wr2 : Wr1;
        ushort* dst = (layer ? WTfrag2 : WTfrag1) + (size_t)idx * 8;
        int lane = idx & 63, tt = (idx >> 6) & 7, s = idx >> 9;
        int col = tt * 16 + (lane & 15);
        int k0 = s * 32 + (lane >> 4) * 8;
        #pragma unroll
        for (int j = 0; j < 8; ++j) {
            int k = k0 + j;
            float v = (k < DD) ? Wl[k * DD + col] : Wr[(k - DD) * DD + col];
            dst[j] = f2bf_rne(v);
        }
    } else {
        int idx = (bx - nxblk - 32) * 256 + t;   // [0, 1024)
        ushort* dst = WoFrag + (size_t)idx * 8;
        int lane = idx & 63, tt = (idx >> 6) & 3, kc = idx >> 8;
        int col = tt * 16 + (lane & 15);
        int k0 = kc * 32 + (lane >> 4) * 8;
        #pragma unroll
        for (int j = 0; j < 8; ++j) {
            dst[j] = f2bf_rne(Wout[(k0 + j) * CC + col]);
        }
    }
}

// ===== FUSED agg + MFMA SAGE layer ==========================================
// Per 16-node tile (grid-stride): phase A = each wave aggregates 4 nodes from
// fp8 rows (proven csr_agg8 body) and writes bf16 mean rows into ping-pong
// LDS sA[pp]; one barrier; phase B = R22 layer (persistent 64-VGPR B-frags,
// mean A-frags from LDS, root from global). Ping-pong + 1 barrier/tile is
// lap-safe (2 barriers needed to lap a buffer).
template <bool PROJ>
__global__ __launch_bounds__(256) void fused_layer_kernel(
    const uint* __restrict__ gq, const ushort* __restrict__ rootH,
    const int* __restrict__ offs, const int* __restrict__ cnt,
    const int* __restrict__ csr,
    const ushort* __restrict__ WTfrag, const float* __restrict__ bias,
    ushort* __restrict__ outH, uchar* __restrict__ outQ,
    const ushort* __restrict__ WoFrag, const float* __restrict__ bout,
    float* __restrict__ outF, int n, int ntiles) {
    __shared__ ushort sA[2][16][136];                    // ping-pong mean tile
    __shared__ ushort sW[PROJ ? 1 : 4][16][40];
    __shared__ __align__(16) uchar sQ[PROJ ? 1 : 4][16][48];
    __shared__ ushort sH[PROJ ? 2 : 1][16][136];
    const int tid = threadIdx.x;
    const int w = tid >> 6;
    const int l = tid & 63;
    const int sub = l >> 4;
    const int li = l & 15;
    const int lrow16 = l & 15;
    const int kb = (l >> 4) * 8;
    const int lcol = l & 15;
    const int lrow0 = (l >> 4) * 4;

    // persistent B: 16 frags (cols w*32 .. w*32+31) = 64 VGPR
    short8v breg[8][2];
    #pragma unroll
    for (int s = 0; s < 8; ++s) {
        #pragma unroll
        for (int t = 0; t < 2; ++t) {
            breg[s][t] = *(const short8v*)(WTfrag + (size_t)s * 4096 +
                                           (w * 2 + t) * 512 + l * 8);
        }
    }
    float bias_r[2];
    #pragma unroll
    for (int t = 0; t < 2; ++t) bias_r[t] = bias[w * 32 + t * 16 + lcol];

    int pp = 0;
    for (int tile = blockIdx.x; tile < ntiles; tile += gridDim.x, pp ^= 1) {
        const int row0 = tile * 16;

        // ---- phase A: aggregate 4 nodes per wave into sA[pp] ----
        for (int nd = 0; nd < 4; ++nd) {
            const int nodec = min(row0 + w * 4 + nd, n - 1);
            const int start = offs[nodec];
            const int c = cnt[nodec];
            f32x2 a[4], aa[4];
            #pragma unroll
            for (int k = 0; k < 4; ++k) {
                a[k] = (f32x2){0.f, 0.f}; aa[k] = (f32x2){0.f, 0.f};
            }
            #define ACC8(A, U) { \
                A[0] += __builtin_amdgcn_cvt_pk_f32_fp8(U.x, false); \
                A[1] += __builtin_amdgcn_cvt_pk_f32_fp8(U.x, true);  \
                A[2] += __builtin_amdgcn_cvt_pk_f32_fp8(U.y, false); \
                A[3] += __builtin_amdgcn_cvt_pk_f32_fp8(U.y, true);  }
            const int c16 = c & ~15;
            int j = 0;
            if (c16 > 0) {
                int s0 = csr[start + sub];
                int s1 = csr[start + 4 + sub];
                int s2 = csr[start + 8 + sub];
                int s3 = csr[start + 12 + sub];
                for (; j < c16; j += 16) {
                    int t0 = 0, t1 = 0, t2 = 0, t3 = 0;
                    if (j + 16 < c16) {
                        t0 = csr[start + j + 16 + sub];
                        t1 = csr[start + j + 20 + sub];
                        t2 = csr[start + j + 24 + sub];
                        t3 = csr[start + j + 28 + sub];
                    }
                    uint2 u0 = *(const uint2*)((const uchar*)gq + (size_t)s0 * DD + li * 8);
                    uint2 u1 = *(const uint2*)((const uchar*)gq + (size_t)s1 * DD + li * 8);
                    uint2 u2 = *(const uint2*)((const uchar*)gq + (size_t)s2 * DD + li * 8);
                    uint2 u3 = *(const uint2*)((const uchar*)gq + (size_t)s3 * DD + li * 8);
                    ACC8(a, u0); ACC8(a, u1); ACC8(aa, u2); ACC8(aa, u3);
                    s0 = t0; s1 = t1; s2 = t2; s3 = t3;
                }
            }
            if (c - j >= 8) {
                int s0 = csr[start + j + sub];
                int s1 = csr[start + j + 4 + sub];
                uint2 u0 = *(const uint2*)((const uchar*)gq + (size_t)s0 * DD + li * 8);
                uint2 u1 = *(const uint2*)((const uchar*)gq + (size_t)s1 * DD + li * 8);
                ACC8(a, u0); ACC8(aa, u1);
                j += 8;
            }
            if (c - j >= 4) {
                int s = csr[start + j + sub];
                uint2 u = *(const uint2*)((const uchar*)gq + (size_t)s * DD + li * 8);
                ACC8(a, u);
                j += 4;
            }
            if (j + sub < c) {
                int s = csr[start + j + sub];
                uint2 u = *(const uint2*)((const uchar*)gq + (size_t)s * DD + li * 8);
                ACC8(aa, u);
            }
            #undef ACC8
            float res[8];
            #pragma unroll
            for (int k = 0; k < 4; ++k) {
                f32x2 v = a[k] + aa[k];
                float e0 = v.x; e0 += __shfl_xor(e0, 16); e0 += __shfl_xor(e0, 32);
                float e1 = v.y; e1 += __shfl_xor(e1, 16); e1 += __shfl_xor(e1, 32);
                res[2 * k] = e0; res[2 * k + 1] = e1;
            }
            if (sub == 0) {
                float inv = 1.0f / fmaxf((float)c, 1.0f);
                short8v o;
                #pragma unroll
                for (int k = 0; k < 8; ++k) o[k] = (short)f2bf_rne(res[k] * inv);
                *(short8v*)&sA[pp][w * 4 + nd][li * 8] = o;
            }
        }
        __syncthreads();   // sA[pp] complete; also fences prior sW/sQ/sH reuse

        // ---- phase B: layer MFMA ----
        const int arowg = min(row0 + lrow16, n - 1);
        const ushort* Ar = rootH + (size_t)arowg * DD;
        short8v ap[8];
        #pragma unroll
        for (int s = 0; s < 8; ++s) {
            ap[s] = (s < 4) ? *(const short8v*)&sA[pp][lrow16][s * 32 + kb]
                            : *(const short8v*)(Ar + (s - 4) * 32 + kb);
        }
        f32x4 acc[2];
        acc[0] = (f32x4){0.f, 0.f, 0.f, 0.f};
        acc[1] = (f32x4){0.f, 0.f, 0.f, 0.f};
        #pragma unroll
        for (int s = 0; s < 8; ++s) {
            acc[0] = __builtin_amdgcn_mfma_f32_16x16x32_bf16(ap[s], breg[s][0],
                                                             acc[0], 0, 0, 0);
            acc[1] = __builtin_amdgcn_mfma_f32_16x16x32_bf16(ap[s], breg[s][1],
                                                             acc[1], 0, 0, 0);
        }

        if (!PROJ) {
            #pragma unroll
            for (int t = 0; t < 2; ++t) {
                #pragma unroll
                for (int r = 0; r < 4; ++r) {
                    float o = fmaxf(acc[t][r] + bias_r[t], 0.f);
                    sW[w][lrow0 + r][t * 16 + lcol] = f2bf_rne(o);
                    sQ[w][lrow0 + r][t * 16 + lcol] = __hip_fp8_e4m3(o).__x;
                }
            }
            {
                int row = l >> 2, seg = l & 3;
                int grow = row0 + row;
                if (grow < n)
                    *(uint4*)(outH + (size_t)grow * DD + w * 32 + seg * 8) =
                        *(const uint4*)&sW[w][row][seg * 8];
            }
            if (l < 32) {
                int row = l >> 1, seg = l & 1;
                int grow = row0 + row;
                if (grow < n)
                    *(uint4*)(outQ + (size_t)grow * DD + w * 32 + seg * 16) =
                        *(const uint4*)&sQ[w][row][seg * 16];
            }
        } else {
            #pragma unroll
            for (int t = 0; t < 2; ++t) {
                #pragma unroll
                for (int r = 0; r < 4; ++r) {
                    sH[pp][lrow0 + r][w * 32 + t * 16 + lcol] =
                        f2bf_rne(fmaxf(acc[t][r] + bias_r[t], 0.f));
                }
            }
            __syncthreads();
            f32x4 po = (f32x4){0.f, 0.f, 0.f, 0.f};
            #pragma unroll
            for (int kc = 0; kc < 4; ++kc) {
                short8v ah = *(const short8v*)&sH[pp][lrow16][kc * 32 + kb];
                short8v bh = *(const short8v*)(WoFrag + (size_t)kc * 2048 +
                                               w * 512 + l * 8);
                po = __builtin_amdgcn_mfma_f32_16x16x32_bf16(ah, bh, po, 0, 0, 0);
            }
            const int col = w * 16 + lcol;
            const float b = bout[col];
            #pragma unroll
            for (int r = 0; r < 4; ++r) {
                int grow = row0 + lrow0 + r;
                if (grow < n) outF[(size_t)grow * CC + col] = po[r] + b;
            }
        }
    }
}

extern "C" void kernel_launch(void* const* d_in, const int* in_sizes, int n_in,
                              void* d_out, int out_size, void* d_ws, size_t ws_size,
                              hipStream_t stream) {
    const float* x    = (const float*)d_in[0];
    const int*   ei   = (const int*)d_in[1];
    const float* W1l  = (const float*)d_in[2];
    const float* b1   = (const float*)d_in[3];
    const float* W1r  = (const float*)d_in[4];
    const float* W2l  = (const float*)d_in[5];
    const float* b2   = (const float*)d_in[6];
    const float* W2r  = (const float*)d_in[7];
    const float* Wout = (const float*)d_in[8];
    const float* bout = (const float*)d_in[9];
    float* out = (float*)d_out;
    const int n = in_sizes[0] / DD;       // 100000
    const int E = in_sizes[1] / 2;        // 1600000
    const size_t NP = (size_t)n * DD;

    const int NBUCK = (n + BKW - 1) / BKW;      // 196

    // workspace (~100 MB); ebuf (196*CAP*4B = 8.03MB) aliases the front of
    // xq (12.8MB): ebuf dead after binB2; prep (writes xq) runs after binB2.
    int* offs  = (int*)d_ws;                              // 100352
    int* cnt   = offs + 100352;                           // 100352
    int* bcur  = cnt + 100352;                            // 256
    int* csr   = bcur + 256;                              // NBUCK*CAP (8.03MB)
    uint* ebuf = (uint*)(csr + NBUCK * CAP);              // NBUCK*CAP
    uint* xq   = ebuf;                                    // n*128 fp8 (12.8MB)
    ushort* xh = (ushort*)((uchar*)xq + NP);              // n*128 bf16
    ushort* h1h = xh + NP;                                // n*128 bf16
    ushort* WTfrag1 = h1h + NP;                           // 32768 ushorts each
    ushort* WTfrag2 = WTfrag1 + 32768;
    ushort* WoFrag  = WTfrag2 + 32768;                    // 8192 ushorts
    uchar* h1q = (uchar*)(WoFrag + 8192);                 // n*128 fp8 (12.8MB)

    binit_kernel<<<1, 256, 0, stream>>>(bcur, NBUCK);
    binA_kernel<<<(E + NPB - 1) / NPB, 256, 0, stream>>>(ei, bcur, ebuf, E);
    binB2_kernel<<<NBUCK, 256, 0, stream>>>(ebuf, bcur, offs, cnt, csr, n);

    const int nxblk = (int)(NP / 8 / 256);    // 6250
    prep_kernel<<<nxblk + 36, 256, 0, stream>>>(x, xh, xq, W1l, W1r, W2l, W2r,
                                                Wout, WTfrag1, WTfrag2, WoFrag, nxblk);

    const int ntiles = (n + 15) / 16;         // 6250
    const int lgrid = 1536;

    fused_layer_kernel<false><<<lgrid, 256, 0, stream>>>(
        xq, xh, offs, cnt, csr, WTfrag1, b1, h1h, h1q,
        (const ushort*)nullptr, (const float*)nullptr, (float*)nullptr, n, ntiles);

    fused_layer_kernel<true><<<lgrid, 256, 0, stream>>>(
        (const uint*)h1q, h1h, offs, cnt, csr, WTfrag2, b2,
        (ushort*)nullptr, (uchar*)nullptr,
        WoFrag, bout, out, n, ntiles);
}

// Round 24
// 205.686 us; speedup vs baseline: 1.4515x; 1.4515x over previous
//
#include <hip/hip_runtime.h>
#include <hip/hip_fp8.h>

#define DD 128
#define CC 64
#define BKW 512            // nodes per bucket
#define NPB 4096           // edges per phase-B block
#define CAP 10240          // per-bucket edge capacity (mean 8192, +22 sigma)

typedef __attribute__((ext_vector_type(8))) short short8v;
typedef __attribute__((ext_vector_type(4))) float f32x4;
typedef __attribute__((ext_vector_type(2))) float f32x2;

static __device__ inline ushort f2bf_rne(float f) {
    unsigned u = __float_as_uint(f);
    unsigned r = (u + 0x7FFFu + ((u >> 16) & 1u)) >> 16;
    return (ushort)r;
}
static __device__ inline float bf2f(ushort h) {
    return __uint_as_float(((unsigned)h) << 16);
}

// ============ bcur init: bucket b appends at b*CAP ============
__global__ void binit_kernel(int* __restrict__ bcur, int nbuck) {
    int b = blockIdx.x * 256 + threadIdx.x;
    if (b < nbuck) bcur[b] = b * CAP;
}

// ===== phase B: bin edges by bucket; packed word = src | (dst&511)<<17 ======
__global__ __launch_bounds__(256) void binA_kernel(const int* __restrict__ ei,
                                                   int* __restrict__ bcur,
                                                   uint* __restrict__ ebuf, int E) {
    __shared__ int sRun[256];
    __shared__ int sRel[256];
    __shared__ int sBase[256];
    __shared__ uint sPair[NPB];
    __shared__ unsigned char sBkt[NPB];
    __shared__ int sHist[256];
    const int t = threadIdx.x;
    const int e0 = blockIdx.x * NPB;
    const int cntE = min(NPB, E - e0);

    sHist[t] = 0;
    __syncthreads();
    for (int j = t; j < cntE; j += 256) {
        int dst = ei[E + e0 + j];
        atomicAdd(&sHist[dst >> 9], 1);
    }
    __syncthreads();
    int h = sHist[t];
    sRun[t] = h;
    __syncthreads();
    for (int off = 1; off < 256; off <<= 1) {
        int v = 0;
        if (t >= off) v = sRun[t - off];
        __syncthreads();
        if (t >= off) sRun[t] += v;
        __syncthreads();
    }
    int runstart = sRun[t] - h;
    int base = 0;
    if (h > 0) base = atomicAdd(&bcur[t], h);
    sRun[t] = runstart;
    sRel[t] = runstart;
    sBase[t] = base;
    __syncthreads();
    for (int j = t; j < cntE; j += 256) {
        int src = ei[e0 + j];
        int dst = ei[E + e0 + j];
        int b = dst >> 9;
        int slot = atomicAdd(&sRel[b], 1);
        sPair[slot] = (uint)src | ((uint)(dst & 511) << 17);
        sBkt[slot] = (unsigned char)b;
    }
    __syncthreads();
    for (int s = t; s < cntE; s += 256) {
        uint p = sPair[s];
        int b = (int)sBkt[s];
        int gpos = sBase[b] + (s - sRun[b]);
        ebuf[gpos] = p;
    }
}

// == phase C: per-bucket (region [b*CAP, bcur[b])): per-node offs/cnt + scatter ==
__global__ __launch_bounds__(256) void binB2_kernel(const uint* __restrict__ ebuf,
                                                    const int* __restrict__ bcur,
                                                    int* __restrict__ offs,
                                                    int* __restrict__ cnt,
                                                    int* __restrict__ csr, int n) {
    __shared__ int sCnt[BKW];
    __shared__ int sOffs[BKW];
    __shared__ int sScan[256];
    const int t = threadIdx.x;
    const int node0 = blockIdx.x * BKW;
    const int start = blockIdx.x * CAP;
    const int end = bcur[blockIdx.x];

    sCnt[t] = 0; sCnt[t + 256] = 0;
    __syncthreads();
    for (int j = start + t; j < end; j += 256) {
        int d = (int)(ebuf[j] >> 17);
        atomicAdd(&sCnt[d], 1);
    }
    __syncthreads();
    int v0 = sCnt[2 * t], v1 = sCnt[2 * t + 1];
    int sum = v0 + v1;
    sScan[t] = sum;
    __syncthreads();
    for (int off = 1; off < 256; off <<= 1) {
        int xv = 0;
        if (t >= off) xv = sScan[t - off];
        __syncthreads();
        if (t >= off) sScan[t] += xv;
        __syncthreads();
    }
    int excl = sScan[t] - sum;
    sOffs[2 * t] = start + excl;
    sOffs[2 * t + 1] = start + excl + v0;
    __syncthreads();
    for (int i = t; i < BKW; i += 256) {
        int node = node0 + i;
        if (node < n) { offs[node] = sOffs[i]; cnt[node] = sCnt[i]; }
    }
    __syncthreads();
    sCnt[t] = 0; sCnt[t + 256] = 0;
    __syncthreads();
    for (int j = start + t; j < end; j += 256) {
        uint p = ebuf[j];
        int d = (int)(p >> 17);
        int r = atomicAdd(&sCnt[d], 1);
        csr[sOffs[d] + r] = (int)(p & 0x1FFFFu);
    }
}

// ===== merged prep: x -> (xh bf16, xq e4m3) + wfrag + wofrag ===============
__global__ __launch_bounds__(256) void prep_kernel(
    const float* __restrict__ x, ushort* __restrict__ xh, uint* __restrict__ xq,
    const float* __restrict__ Wl1, const float* __restrict__ Wr1,
    const float* __restrict__ Wl2, const float* __restrict__ Wr2,
    const float* __restrict__ Wout,
    ushort* __restrict__ WTfrag1, ushort* __restrict__ WTfrag2,
    ushort* __restrict__ WoFrag, int nxblk) {
    const int t = threadIdx.x;
    const int bx = blockIdx.x;
    if (bx < nxblk) {
        int i = bx * 256 + t;                    // 8 elems per thread
        float4 a = ((const float4*)x)[2 * i];
        float4 b = ((const float4*)x)[2 * i + 1];
        float vv[8] = {a.x, a.y, a.z, a.w, b.x, b.y, b.z, b.w};
        ushort r[8];
        uint q[8];
        #pragma unroll
        for (int j = 0; j < 8; ++j) {
            r[j] = f2bf_rne(vv[j]);
            q[j] = (uint)__hip_fp8_e4m3(vv[j]).__x;
        }
        uint4 o;
        o.x = (uint)r[0] | ((uint)r[1] << 16);
        o.y = (uint)r[2] | ((uint)r[3] << 16);
        o.z = (uint)r[4] | ((uint)r[5] << 16);
        o.w = (uint)r[6] | ((uint)r[7] << 16);
        ((uint4*)xh)[i] = o;
        uint2 oq;
        oq.x = q[0] | (q[1] << 8) | (q[2] << 16) | (q[3] << 24);
        oq.y = q[4] | (q[5] << 8) | (q[6] << 16) | (q[7] << 24);
        ((uint2*)xq)[i] = oq;
    } else if (bx < nxblk + 32) {
        int li = bx - nxblk;
        int layer = li >> 4;
        int idx = (li & 15) * 256 + t;           // [0, 4096)
        const float* Wl = layer ? Wl2 : Wl1;
        const float* Wr = layer ? Wr2 : Wr1;
        ushort* dst = (layer ? WTfrag2 : WTfrag1) + (size_t)idx * 8;
        int lane = idx & 63, tt = (idx >> 6) & 7, s = idx >> 9;
        int col = tt * 16 + (lane & 15);
        int k0 = s * 32 + (lane >> 4) * 8;
        #pragma unroll
        for (int j = 0; j < 8; ++j) {
            int k = k0 + j;
            float v = (k < DD) ? Wl[k * DD + col] : Wr[(k - DD) * DD + col];
            dst[j] = f2bf_rne(v);
        }
    } else {
        int idx = (bx - nxblk - 32) * 256 + t;   // [0, 1024)
        ushort* dst = WoFrag + (size_t)idx * 8;
        int lane = idx & 63, tt = (idx >> 6) & 3, kc = idx >> 8;
        int col = tt * 16 + (lane & 15);
        int k0 = kc * 32 + (lane >> 4) * 8;
        #pragma unroll
        for (int j = 0; j < 8; ++j) {
            dst[j] = f2bf_rne(Wout[(k0 + j) * CC + col]);
        }
    }
}

// ====== CSR gather-aggregate, fp8 rows, uint2 lanes: 16 nbrs in flight ======
// lane = (sub 0-3: neighbor slot, li 0-15: 8-dim chunk). Proven R17 form.
__global__ __launch_bounds__(256) void csr_agg8_kernel(
    const uint* __restrict__ xq, const int* __restrict__ offs,
    const int* __restrict__ cnt, const int* __restrict__ csr,
    ushort* __restrict__ meanH, int n) {
    int node = blockIdx.x * 4 + (threadIdx.x >> 6);
    if (node >= n) return;
    const int lane = threadIdx.x & 63;
    const int sub = lane >> 4;
    const int li = lane & 15;
    const int start = offs[node];
    const int c = cnt[node];
    f32x2 a[4], aa[4];
    #pragma unroll
    for (int k = 0; k < 4; ++k) { a[k] = (f32x2){0.f, 0.f}; aa[k] = (f32x2){0.f, 0.f}; }
    #define ACC8(A, U) { \
        A[0] += __builtin_amdgcn_cvt_pk_f32_fp8(U.x, false); \
        A[1] += __builtin_amdgcn_cvt_pk_f32_fp8(U.x, true);  \
        A[2] += __builtin_amdgcn_cvt_pk_f32_fp8(U.y, false); \
        A[3] += __builtin_amdgcn_cvt_pk_f32_fp8(U.y, true);  }
    const int c16 = c & ~15;
    int j = 0;
    if (c16 > 0) {
        int s0 = csr[start + sub];
        int s1 = csr[start + 4 + sub];
        int s2 = csr[start + 8 + sub];
        int s3 = csr[start + 12 + sub];
        for (; j < c16; j += 16) {
            int t0 = 0, t1 = 0, t2 = 0, t3 = 0;
            if (j + 16 < c16) {
                t0 = csr[start + j + 16 + sub];
                t1 = csr[start + j + 20 + sub];
                t2 = csr[start + j + 24 + sub];
                t3 = csr[start + j + 28 + sub];
            }
            uint2 u0 = *(const uint2*)((const uchar*)xq + (size_t)s0 * DD + li * 8);
            uint2 u1 = *(const uint2*)((const uchar*)xq + (size_t)s1 * DD + li * 8);
            uint2 u2 = *(const uint2*)((const uchar*)xq + (size_t)s2 * DD + li * 8);
            uint2 u3 = *(const uint2*)((const uchar*)xq + (size_t)s3 * DD + li * 8);
            ACC8(a, u0); ACC8(a, u1); ACC8(aa, u2); ACC8(aa, u3);
            s0 = t0; s1 = t1; s2 = t2; s3 = t3;
        }
    }
    if (c - j >= 8) {
        int s0 = csr[start + j + sub];
        int s1 = csr[start + j + 4 + sub];
        uint2 u0 = *(const uint2*)((const uchar*)xq + (size_t)s0 * DD + li * 8);
        uint2 u1 = *(const uint2*)((const uchar*)xq + (size_t)s1 * DD + li * 8);
        ACC8(a, u0); ACC8(aa, u1);
        j += 8;
    }
    if (c - j >= 4) {
        int s = csr[start + j + sub];
        uint2 u = *(const uint2*)((const uchar*)xq + (size_t)s * DD + li * 8);
        ACC8(a, u);
        j += 4;
    }
    if (j + sub < c) {
        int s = csr[start + j + sub];
        uint2 u = *(const uint2*)((const uchar*)xq + (size_t)s * DD + li * 8);
        ACC8(aa, u);
    }
    #undef ACC8
    float res[8];
    #pragma unroll
    for (int k = 0; k < 4; ++k) {
        f32x2 v = a[k] + aa[k];
        float e0 = v.x; e0 += __shfl_xor(e0, 16); e0 += __shfl_xor(e0, 32);
        float e1 = v.y; e1 += __shfl_xor(e1, 16); e1 += __shfl_xor(e1, 32);
        res[2 * k] = e0; res[2 * k + 1] = e1;
    }
    if (sub == 0) {
        float inv = 1.0f / fmaxf((float)c, 1.0f);
        short8v o;
        #pragma unroll
        for (int k = 0; k < 8; ++k) o[k] = (short)f2bf_rne(res[k] * inv);
        *(short8v*)(meanH + (size_t)node * DD + li * 8) = o;
    }
}

// ===== MFMA SAGE layer: 16-row tiles, wave = col-quarter (B in 64 VGPR) =====
template <bool PROJ>
__global__ __launch_bounds__(256) void layer_mfma_kernel(
    const ushort* __restrict__ meanH, const ushort* __restrict__ rootH,
    const ushort* __restrict__ WTfrag, const float* __restrict__ bias,
    ushort* __restrict__ outH, uchar* __restrict__ outQ,
    const ushort* __restrict__ WoFrag, const float* __restrict__ bout,
    float* __restrict__ outF, int n, int ntiles) {
    __shared__ ushort sW[PROJ ? 1 : 4][16][40];
    __shared__ __align__(16) uchar sQ[PROJ ? 1 : 4][16][48];
    __shared__ ushort sH[PROJ ? 2 : 1][16][136];
    const int tid = threadIdx.x;
    const int w = tid >> 6;
    const int l = tid & 63;
    const int lrow16 = l & 15;
    const int kb = (l >> 4) * 8;
    const int lcol = l & 15;
    const int lrow0 = (l >> 4) * 4;

    short8v breg[8][2];
    #pragma unroll
    for (int s = 0; s < 8; ++s) {
        #pragma unroll
        for (int t = 0; t < 2; ++t) {
            breg[s][t] = *(const short8v*)(WTfrag + (size_t)s * 4096 +
                                           (w * 2 + t) * 512 + l * 8);
        }
    }
    float bias_r[2];
    #pragma unroll
    for (int t = 0; t < 2; ++t) bias_r[t] = bias[w * 32 + t * 16 + lcol];

    int pp = 0;
    for (int tile = blockIdx.x; tile < ntiles; tile += gridDim.x, pp ^= 1) {
        const int row0 = tile * 16;
        const int arowg = min(row0 + lrow16, n - 1);
        const ushort* Am = meanH + (size_t)arowg * DD;
        const ushort* Ar = rootH + (size_t)arowg * DD;
        short8v ap[8];
        #pragma unroll
        for (int s = 0; s < 8; ++s) {
            ap[s] = (s < 4) ? *(const short8v*)(Am + s * 32 + kb)
                            : *(const short8v*)(Ar + (s - 4) * 32 + kb);
        }
        f32x4 acc[2];
        acc[0] = (f32x4){0.f, 0.f, 0.f, 0.f};
        acc[1] = (f32x4){0.f, 0.f, 0.f, 0.f};
        #pragma unroll
        for (int s = 0; s < 8; ++s) {
            acc[0] = __builtin_amdgcn_mfma_f32_16x16x32_bf16(ap[s], breg[s][0],
                                                             acc[0], 0, 0, 0);
            acc[1] = __builtin_amdgcn_mfma_f32_16x16x32_bf16(ap[s], breg[s][1],
                                                             acc[1], 0, 0, 0);
        }

        if (!PROJ) {
            #pragma unroll
            for (int t = 0; t < 2; ++t) {
                #pragma unroll
                for (int r = 0; r < 4; ++r) {
                    float o = fmaxf(acc[t][r] + bias_r[t], 0.f);
                    sW[w][lrow0 + r][t * 16 + lcol] = f2bf_rne(o);
                    sQ[w][lrow0 + r][t * 16 + lcol] = __hip_fp8_e4m3(o).__x;
                }
            }
            {
                int row = l >> 2, seg = l & 3;
                int grow = row0 + row;
                if (grow < n)
                    *(uint4*)(outH + (size_t)grow * DD + w * 32 + seg * 8) =
                        *(const uint4*)&sW[w][row][seg * 8];
            }
            if (l < 32) {
                int row = l >> 1, seg = l & 1;
                int grow = row0 + row;
                if (grow < n)
                    *(uint4*)(outQ + (size_t)grow * DD + w * 32 + seg * 16) =
                        *(const uint4*)&sQ[w][row][seg * 16];
            }
        } else {
            #pragma unroll
            for (int t = 0; t < 2; ++t) {
                #pragma unroll
                for (int r = 0; r < 4; ++r) {
                    sH[pp][lrow0 + r][w * 32 + t * 16 + lcol] =
                        f2bf_rne(fmaxf(acc[t][r] + bias_r[t], 0.f));
                }
            }
            __syncthreads();
            f32x4 po = (f32x4){0.f, 0.f, 0.f, 0.f};
            #pragma unroll
            for (int kc = 0; kc < 4; ++kc) {
                short8v ah = *(const short8v*)&sH[pp][lrow16][kc * 32 + kb];
                short8v bh = *(const short8v*)(WoFrag + (size_t)kc * 2048 +
                                               w * 512 + l * 8);
                po = __builtin_amdgcn_mfma_f32_16x16x32_bf16(ah, bh, po, 0, 0, 0);
            }
            const int col = w * 16 + lcol;
            const float b = bout[col];
            #pragma unroll
            for (int r = 0; r < 4; ++r) {
                int grow = row0 + lrow0 + r;
                if (grow < n) outF[(size_t)grow * CC + col] = po[r] + b;
            }
        }
    }
}

extern "C" void kernel_launch(void* const* d_in, const int* in_sizes, int n_in,
                              void* d_out, int out_size, void* d_ws, size_t ws_size,
                              hipStream_t stream) {
    const float* x    = (const float*)d_in[0];
    const int*   ei   = (const int*)d_in[1];
    const float* W1l  = (const float*)d_in[2];
    const float* b1   = (const float*)d_in[3];
    const float* W1r  = (const float*)d_in[4];
    const float* W2l  = (const float*)d_in[5];
    const float* b2   = (const float*)d_in[6];
    const float* W2r  = (const float*)d_in[7];
    const float* Wout = (const float*)d_in[8];
    const float* bout = (const float*)d_in[9];
    float* out = (float*)d_out;
    const int n = in_sizes[0] / DD;       // 100000
    const int E = in_sizes[1] / 2;        // 1600000
    const size_t NP = (size_t)n * DD;

    const int NBUCK = (n + BKW - 1) / BKW;      // 196

    // workspace (~112 MB); ebuf (196*CAP*4B = 8.03MB) aliases the front of
    // xq (12.8MB): ebuf dead after binB2; prep (writes xq) runs after binB2.
    int* offs  = (int*)d_ws;                              // 100352
    int* cnt   = offs + 100352;                           // 100352
    int* bcur  = cnt + 100352;                            // 256
    int* csr   = bcur + 256;                              // NBUCK*CAP (8.03MB)
    uint* ebuf = (uint*)(csr + NBUCK * CAP);              // NBUCK*CAP
    uint* xq   = ebuf;                                    // n*128 fp8 (12.8MB)
    ushort* xh = (ushort*)((uchar*)xq + NP);              // n*128 bf16
    ushort* meanH = xh + NP;                              // n*128 bf16
    ushort* h1h = meanH + NP;                             // n*128 bf16
    ushort* WTfrag1 = h1h + NP;                           // 32768 ushorts each
    ushort* WTfrag2 = WTfrag1 + 32768;
    ushort* WoFrag  = WTfrag2 + 32768;                    // 8192 ushorts
    uchar* h1q = (uchar*)(WoFrag + 8192);                 // n*128 fp8 (12.8MB)

    binit_kernel<<<1, 256, 0, stream>>>(bcur, NBUCK);
    binA_kernel<<<(E + NPB - 1) / NPB, 256, 0, stream>>>(ei, bcur, ebuf, E);
    binB2_kernel<<<NBUCK, 256, 0, stream>>>(ebuf, bcur, offs, cnt, csr, n);

    const int nxblk = (int)(NP / 8 / 256);    // 6250
    prep_kernel<<<nxblk + 36, 256, 0, stream>>>(x, xh, xq, W1l, W1r, W2l, W2r,
                                                Wout, WTfrag1, WTfrag2, WoFrag, nxblk);

    const int ntiles = (n + 15) / 16;         // 6250
    const int lgrid = 1024;
    const int ablk = (n + 3) / 4;

    csr_agg8_kernel<<<ablk, 256, 0, stream>>>(xq, offs, cnt, csr, meanH, n);
    layer_mfma_kernel<false><<<lgrid, 256, 0, stream>>>(
        meanH, xh, WTfrag1, b1, h1h, h1q,
        (const ushort*)nullptr, (const float*)nullptr, (float*)nullptr, n, ntiles);

    csr_agg8_kernel<<<ablk, 256, 0, stream>>>((const uint*)h1q, offs, cnt, csr, meanH, n);
    layer_mfma_kernel<true><<<lgrid, 256, 0, stream>>>(
        meanH, h1h, WTfrag2, b2, (ushort*)nullptr, (uchar*)nullptr,
        WoFrag, bout, out, n, ntiles);
}